// Round 1
// baseline (240.838 us; speedup 1.0000x reference)
//
#include <hip/hip_runtime.h>

// y = W @ x + bias, W in COO (rows sorted), fp32.
// Inputs: d_in[0]=vals[nnz] f32, d_in[1]=x[n_cols] f32, d_in[2]=bias[n_rows] f32,
//         d_in[3]=rows[nnz] i32, d_in[4]=cols[nnz] i32, d_in[5]=n_rows scalar i32.
// Output: d_out = y[n_rows] f32.

constexpr int CHUNK = 8;  // nnz per thread; 2x float4/int4 vector loads

__global__ void init_y_bias(const float* __restrict__ bias,
                            float* __restrict__ y, int n) {
    int i = blockIdx.x * blockDim.x + threadIdx.x;
    if (i < n) y[i] = bias[i];
}

__global__ __launch_bounds__(256) void spmv_coo_seg(
        const float* __restrict__ vals,
        const float* __restrict__ x,
        const int*   __restrict__ rows,
        const int*   __restrict__ cols,
        float*       __restrict__ y,
        long long nnz) {
    long long t  = (long long)blockIdx.x * blockDim.x + threadIdx.x;
    long long i0 = t * CHUNK;
    if (i0 >= nnz) return;

    if (i0 + CHUNK <= nnz) {
        // vectorized path: 16B-aligned since i0 % 8 == 0
        const float4* v4 = reinterpret_cast<const float4*>(vals + i0);
        const int4*   r4 = reinterpret_cast<const int4*>(rows + i0);
        const int4*   c4 = reinterpret_cast<const int4*>(cols + i0);
        float4 va = v4[0], vb = v4[1];
        int4   ra = r4[0], rb = r4[1];
        int4   ca = c4[0], cb = c4[1];

        float v[CHUNK] = {va.x, va.y, va.z, va.w, vb.x, vb.y, vb.z, vb.w};
        int   r[CHUNK] = {ra.x, ra.y, ra.z, ra.w, rb.x, rb.y, rb.z, rb.w};
        int   c[CHUNK] = {ca.x, ca.y, ca.z, ca.w, cb.x, cb.y, cb.z, cb.w};

        // issue all gathers up front for MLP
        float g[CHUNK];
        #pragma unroll
        for (int k = 0; k < CHUNK; ++k) g[k] = x[c[k]];

        float sum = 0.f;
        int   cur = r[0];
        #pragma unroll
        for (int k = 0; k < CHUNK; ++k) {
            if (r[k] != cur) {           // row boundary: flush partial
                atomicAdd(&y[cur], sum);
                sum = 0.f;
                cur = r[k];
            }
            sum += v[k] * g[k];
        }
        atomicAdd(&y[cur], sum);
    } else {
        // scalar tail (nnz % CHUNK != 0)
        float sum = 0.f;
        int   cur = rows[i0];
        for (long long k = i0; k < nnz; ++k) {
            int rk = rows[k];
            if (rk != cur) {
                atomicAdd(&y[cur], sum);
                sum = 0.f;
                cur = rk;
            }
            sum += vals[k] * x[cols[k]];
        }
        atomicAdd(&y[cur], sum);
    }
}

extern "C" void kernel_launch(void* const* d_in, const int* in_sizes, int n_in,
                              void* d_out, int out_size, void* d_ws, size_t ws_size,
                              hipStream_t stream) {
    const float* vals = (const float*)d_in[0];
    const float* x    = (const float*)d_in[1];
    const float* bias = (const float*)d_in[2];
    const int*   rows = (const int*)d_in[3];
    const int*   cols = (const int*)d_in[4];
    float* y = (float*)d_out;

    const long long nnz = in_sizes[0];
    const int n_rows    = in_sizes[2];   // len(bias) == n_rows

    // 1) y = bias (d_out is poisoned before every timed call)
    {
        int threads = 256;
        int blocks  = (n_rows + threads - 1) / threads;
        init_y_bias<<<blocks, threads, 0, stream>>>(bias, y, n_rows);
    }

    // 2) segmented COO accumulate
    {
        long long n_thr = (nnz + CHUNK - 1) / CHUNK;
        int threads = 256;
        long long blocks = (n_thr + threads - 1) / threads;
        spmv_coo_seg<<<(int)blocks, threads, 0, stream>>>(vals, x, rows, cols, y, nnz);
    }
}